// Round 1
// baseline (249.753 us; speedup 1.0000x reference)
//
#include <hip/hip_runtime.h>
#include <math.h>

#define F_IN 10000
#define NROWS 4096
// 40 chunks of 256 columns cover 10000 (last chunk only 16 valid cols)
#define NCHUNK 40
#define CGROUPS 8
#define ROWS_PER_WAVE 8

// d_ws layout: 9 float arrays of F_IN each, column-ordered:
//   [0..2]*F_IN : A_m = 1/(std*sqrt(2))
//   [3..5]*F_IN : B_m = -mean/(std*sqrt(2))
//   [6..8]*F_IN : C_m = logw_m - log(std) - 0.5*log(2*pi)
__global__ void spn_prep_kernel(const float* __restrict__ means,
                                const float* __restrict__ stds,
                                const float* __restrict__ w1,
                                const int* __restrict__ rand_idxs,
                                float* __restrict__ ws,
                                float* __restrict__ out) {
    int f = blockIdx.x * blockDim.x + threadIdx.x;
    if (f < NROWS) out[f] = 0.0f;           // zero the output for atomic accumulation
    if (f >= F_IN) return;

    int j = rand_idxs[f];                   // column of x this feature reads

    float wa = w1[f * 3 + 0];
    float wb = w1[f * 3 + 1];
    float wc = w1[f * 3 + 2];
    float wm = fmaxf(fmaxf(wa, wb), wc);
    float lse = wm + __logf(__expf(wa - wm) + __expf(wb - wm) + __expf(wc - wm));

    const float INV_SQRT2 = 0.70710678118654752440f;
    const float HALF_LOG_2PI = 0.91893853320467274178f;

#pragma unroll
    for (int m = 0; m < 3; m++) {
        float w  = w1[f * 3 + m] - lse;     // log_softmax
        float sd = stds[f * 3 + m];
        float mu = means[f * 3 + m];
        float a  = INV_SQRT2 / sd;          // fold the 1/2 of -0.5*z^2 into the scale
        float b  = -mu * a;
        float c  = w - __logf(sd) - HALF_LOG_2PI;
        ws[(0 + m) * F_IN + j] = a;
        ws[(3 + m) * F_IN + j] = b;
        ws[(6 + m) * F_IN + j] = c;
    }
}

// per-column mixture term: returns max-of-3 logprobs and s = sum exp(v - max), s in [1,3]
__device__ __forceinline__ void col_term(float xv,
                                         float a0, float b0, float c0,
                                         float a1, float b1, float c1,
                                         float a2, float b2, float c2,
                                         float& mx_out, float& s_out) {
    float u0 = fmaf(xv, a0, b0);            // z/sqrt(2)
    float u1 = fmaf(xv, a1, b1);
    float u2 = fmaf(xv, a2, b2);
    float v0 = fmaf(-u0, u0, c0);           // c - z^2/2
    float v1 = fmaf(-u1, u1, c1);
    float v2 = fmaf(-u2, u2, c2);
    float mx = fmaxf(fmaxf(v0, v1), v2);
    float me = __builtin_amdgcn_fmed3f(v0, v1, v2);
    float mn = fminf(fminf(v0, v1), v2);
    float s  = 1.0f + __expf(me - mx) + __expf(mn - mx);
    mx_out = mx;
    s_out  = s;
}

__global__ __launch_bounds__(256) void spn_main_kernel(const float* __restrict__ x,
                                                       const float* __restrict__ ws,
                                                       float* __restrict__ out) {
    const int wave = threadIdx.x >> 6;
    const int lane = threadIdx.x & 63;
    const int rb   = blockIdx.x >> 3;       // row-block: 0..127, 32 rows each
    const int cg   = blockIdx.x & 7;        // column-group: 0..7
    const int row0 = rb * 32 + wave * ROWS_PER_WAVE;

    float accm[ROWS_PER_WAVE];              // sum of per-feature maxes
    float prod[ROWS_PER_WAVE];              // product of s factors (<= 3^20, safe)
#pragma unroll
    for (int r = 0; r < ROWS_PER_WAVE; r++) { accm[r] = 0.0f; prod[r] = 1.0f; }

    for (int c = cg; c < NCHUNK; c += CGROUPS) {
        int j4 = c * 256 + lane * 4;        // this lane's 4 consecutive columns
        // j4 is a multiple of 4, so all 4 columns share the same validity
        bool valid = (j4 < F_IN);
        int jc = valid ? j4 : 0;
        int q  = jc >> 2;

        const float4 A0 = ((const float4*)(ws + 0 * F_IN))[q];
        const float4 A1 = ((const float4*)(ws + 1 * F_IN))[q];
        const float4 A2 = ((const float4*)(ws + 2 * F_IN))[q];
        const float4 B0 = ((const float4*)(ws + 3 * F_IN))[q];
        const float4 B1 = ((const float4*)(ws + 4 * F_IN))[q];
        const float4 B2 = ((const float4*)(ws + 5 * F_IN))[q];
        const float4 C0 = ((const float4*)(ws + 6 * F_IN))[q];
        const float4 C1 = ((const float4*)(ws + 7 * F_IN))[q];
        const float4 C2 = ((const float4*)(ws + 8 * F_IN))[q];

#pragma unroll
        for (int r = 0; r < ROWS_PER_WAVE; r++) {
            const float4 xv = *(const float4*)(x + (row0 + r) * F_IN + jc);

            float m0, s0, m1, s1, m2, s2, m3, s3;
            col_term(xv.x, A0.x, B0.x, C0.x, A1.x, B1.x, C1.x, A2.x, B2.x, C2.x, m0, s0);
            col_term(xv.y, A0.y, B0.y, C0.y, A1.y, B1.y, C1.y, A2.y, B2.y, C2.y, m1, s1);
            col_term(xv.z, A0.z, B0.z, C0.z, A1.z, B1.z, C1.z, A2.z, B2.z, C2.z, m2, s2);
            col_term(xv.w, A0.w, B0.w, C0.w, A1.w, B1.w, C1.w, A2.w, B2.w, C2.w, m3, s3);

            float smx = (m0 + m1) + (m2 + m3);
            float sp  = (s0 * s1) * (s2 * s3);
            accm[r] += valid ? smx : 0.0f;
            prod[r] *= valid ? sp : 1.0f;
        }
    }

#pragma unroll
    for (int r = 0; r < ROWS_PER_WAVE; r++) {
        float part = accm[r] + __logf(prod[r]);
#pragma unroll
        for (int off = 32; off > 0; off >>= 1)
            part += __shfl_xor(part, off, 64);
        if (lane == 0)
            atomicAdd(&out[row0 + r], part);
    }
}

extern "C" void kernel_launch(void* const* d_in, const int* in_sizes, int n_in,
                              void* d_out, int out_size, void* d_ws, size_t ws_size,
                              hipStream_t stream) {
    const float* x         = (const float*)d_in[0];
    const float* means     = (const float*)d_in[1];
    const float* stds      = (const float*)d_in[2];
    const float* w1        = (const float*)d_in[3];
    // w2..w5 (d_in[4..7]) are identity under log_softmax over a size-1 axis
    const int*   rand_idxs = (const int*)d_in[8];

    float* out = (float*)d_out;
    float* ws  = (float*)d_ws;   // needs 9 * 10000 * 4 B = 360 KB

    // prep: column-ordered constants + zero the output
    spn_prep_kernel<<<(F_IN + 255) / 256, 256, 0, stream>>>(means, stds, w1, rand_idxs, ws, out);

    // main: 128 row-blocks (32 rows) x 8 column-groups
    spn_main_kernel<<<128 * CGROUPS, 256, 0, stream>>>(x, ws, out);
}

// Round 2
// 246.380 us; speedup vs baseline: 1.0137x; 1.0137x over previous
//
#include <hip/hip_runtime.h>
#include <math.h>

#define F_IN 10000
#define NROWS 4096
// 40 chunks of 256 columns cover 10000 (last chunk only 16 valid cols)
#define NCHUNK 40
#define CGROUPS 8
#define ROWS_PER_WAVE 4   // 4 rows/wave x 4 waves = 16 rows/block; 256 row-blocks x 8 cg = 2048 blocks

// d_ws layout: 9 float arrays of F_IN each, column-ordered:
//   [0..2]*F_IN : A_m = 1/(std*sqrt(2))
//   [3..5]*F_IN : B_m = -mean/(std*sqrt(2))
//   [6..8]*F_IN : C_m = logw_m - log(std) - 0.5*log(2*pi)
__global__ void spn_prep_kernel(const float* __restrict__ means,
                                const float* __restrict__ stds,
                                const float* __restrict__ w1,
                                const int* __restrict__ rand_idxs,
                                float* __restrict__ ws,
                                float* __restrict__ out) {
    int f = blockIdx.x * blockDim.x + threadIdx.x;
    if (f < NROWS) out[f] = 0.0f;           // zero the output for atomic accumulation
    if (f >= F_IN) return;

    int j = rand_idxs[f];                   // column of x this feature reads

    float wa = w1[f * 3 + 0];
    float wb = w1[f * 3 + 1];
    float wc = w1[f * 3 + 2];
    float wm = fmaxf(fmaxf(wa, wb), wc);
    float lse = wm + __logf(__expf(wa - wm) + __expf(wb - wm) + __expf(wc - wm));

    const float INV_SQRT2 = 0.70710678118654752440f;
    const float HALF_LOG_2PI = 0.91893853320467274178f;

#pragma unroll
    for (int m = 0; m < 3; m++) {
        float w  = w1[f * 3 + m] - lse;     // log_softmax
        float sd = stds[f * 3 + m];
        float mu = means[f * 3 + m];
        float a  = INV_SQRT2 / sd;          // fold the 1/2 of -0.5*z^2 into the scale
        float b  = -mu * a;
        float c  = w - __logf(sd) - HALF_LOG_2PI;
        ws[(0 + m) * F_IN + j] = a;
        ws[(3 + m) * F_IN + j] = b;
        ws[(6 + m) * F_IN + j] = c;
    }
}

// per-column mixture term: returns max-of-3 logprobs and s = sum exp(v - max), s in [1,3]
__device__ __forceinline__ void col_term(float xv,
                                         float a0, float b0, float c0,
                                         float a1, float b1, float c1,
                                         float a2, float b2, float c2,
                                         float& mx_out, float& s_out) {
    float u0 = fmaf(xv, a0, b0);            // z/sqrt(2)
    float u1 = fmaf(xv, a1, b1);
    float u2 = fmaf(xv, a2, b2);
    float v0 = fmaf(-u0, u0, c0);           // c - z^2/2
    float v1 = fmaf(-u1, u1, c1);
    float v2 = fmaf(-u2, u2, c2);
    float mx = fmaxf(fmaxf(v0, v1), v2);
    float me = __builtin_amdgcn_fmed3f(v0, v1, v2);
    float mn = fminf(fminf(v0, v1), v2);
    float s  = 1.0f + __expf(me - mx) + __expf(mn - mx);
    mx_out = mx;
    s_out  = s;
}

__global__ __launch_bounds__(256) void spn_main_kernel(const float* __restrict__ x,
                                                       const float* __restrict__ ws,
                                                       float* __restrict__ out) {
    const int wave = threadIdx.x >> 6;
    const int lane = threadIdx.x & 63;
    const int rb   = blockIdx.x >> 3;       // row-block: 0..255, 16 rows each
    const int cg   = blockIdx.x & 7;        // column-group: 0..7
    const int row0 = rb * (ROWS_PER_WAVE * 4) + wave * ROWS_PER_WAVE;

    float accm[ROWS_PER_WAVE];              // sum of per-feature maxes
    float prod[ROWS_PER_WAVE];              // product of s factors (<= 3^20, safe)
#pragma unroll
    for (int r = 0; r < ROWS_PER_WAVE; r++) { accm[r] = 0.0f; prod[r] = 1.0f; }

    const float* xr[ROWS_PER_WAVE];
#pragma unroll
    for (int r = 0; r < ROWS_PER_WAVE; r++) xr[r] = x + (size_t)(row0 + r) * F_IN;

    // chunk schedule for this cg: c = cg + it*8, it = 0..4 (always exactly 5)
    // prologue: issue x loads for first chunk (cg < 8 -> always fully valid)
    float4 xv[ROWS_PER_WAVE];
    {
        int jc = cg * 256 + lane * 4;
#pragma unroll
        for (int r = 0; r < ROWS_PER_WAVE; r++)
            xv[r] = *(const float4*)(xr[r] + jc);
    }

#pragma unroll
    for (int it = 0; it < 5; ++it) {
        const int c = cg + it * 8;
        const int jcur = c * 256 + lane * 4;
        const bool vcur = (jcur < F_IN);    // only chunk 39's high lanes are invalid
        const int q = vcur ? (jcur >> 2) : 0;

        // params for the current chunk (L2-hot after first touch)
        const float4 A0 = ((const float4*)(ws + 0 * F_IN))[q];
        const float4 A1 = ((const float4*)(ws + 1 * F_IN))[q];
        const float4 A2 = ((const float4*)(ws + 2 * F_IN))[q];
        const float4 B0 = ((const float4*)(ws + 3 * F_IN))[q];
        const float4 B1 = ((const float4*)(ws + 4 * F_IN))[q];
        const float4 B2 = ((const float4*)(ws + 5 * F_IN))[q];
        const float4 C0 = ((const float4*)(ws + 6 * F_IN))[q];
        const float4 C1 = ((const float4*)(ws + 7 * F_IN))[q];
        const float4 C2 = ((const float4*)(ws + 8 * F_IN))[q];

        // software-pipeline: issue next chunk's x loads (HBM) before computing
        float4 xn[ROWS_PER_WAVE];
        if (it < 4) {
            int jn = (c + 8) * 256 + lane * 4;
            int jnc = (jn < F_IN) ? jn : 0;
#pragma unroll
            for (int r = 0; r < ROWS_PER_WAVE; r++)
                xn[r] = *(const float4*)(xr[r] + jnc);
        }

#pragma unroll
        for (int r = 0; r < ROWS_PER_WAVE; r++) {
            float m0, s0, m1, s1, m2, s2, m3, s3;
            col_term(xv[r].x, A0.x, B0.x, C0.x, A1.x, B1.x, C1.x, A2.x, B2.x, C2.x, m0, s0);
            col_term(xv[r].y, A0.y, B0.y, C0.y, A1.y, B1.y, C1.y, A2.y, B2.y, C2.y, m1, s1);
            col_term(xv[r].z, A0.z, B0.z, C0.z, A1.z, B1.z, C1.z, A2.z, B2.z, C2.z, m2, s2);
            col_term(xv[r].w, A0.w, B0.w, C0.w, A1.w, B1.w, C1.w, A2.w, B2.w, C2.w, m3, s3);

            float smx = (m0 + m1) + (m2 + m3);
            float sp  = (s0 * s1) * (s2 * s3);
            accm[r] += vcur ? smx : 0.0f;
            prod[r] *= vcur ? sp : 1.0f;
        }

        if (it < 4) {
#pragma unroll
            for (int r = 0; r < ROWS_PER_WAVE; r++) xv[r] = xn[r];
        }
    }

#pragma unroll
    for (int r = 0; r < ROWS_PER_WAVE; r++) {
        float part = accm[r] + __logf(prod[r]);
#pragma unroll
        for (int off = 32; off > 0; off >>= 1)
            part += __shfl_xor(part, off, 64);
        if (lane == 0)
            atomicAdd(&out[row0 + r], part);
    }
}

extern "C" void kernel_launch(void* const* d_in, const int* in_sizes, int n_in,
                              void* d_out, int out_size, void* d_ws, size_t ws_size,
                              hipStream_t stream) {
    const float* x         = (const float*)d_in[0];
    const float* means     = (const float*)d_in[1];
    const float* stds      = (const float*)d_in[2];
    const float* w1        = (const float*)d_in[3];
    // w2..w5 (d_in[4..7]) are identity under log_softmax over a size-1 axis
    const int*   rand_idxs = (const int*)d_in[8];

    float* out = (float*)d_out;
    float* ws  = (float*)d_ws;   // needs 9 * 10000 * 4 B = 360 KB

    // prep: column-ordered constants + zero the output
    spn_prep_kernel<<<(F_IN + 255) / 256, 256, 0, stream>>>(means, stds, w1, rand_idxs, ws, out);

    // main: 256 row-blocks (16 rows) x 8 column-groups = 2048 blocks
    spn_main_kernel<<<256 * CGROUPS, 256, 0, stream>>>(x, ws, out);
}